// Round 3
// baseline (270.928 us; speedup 1.0000x reference)
//
#include <hip/hip_runtime.h>
#include <float.h>

#define N_VOX 32768
#define N_CODES 8192
#define DIM 64

// output float offsets (flat, in return order)
#define Q_OFF 0
#define VQ_OFF (N_VOX * DIM)      // 2097152
#define CM_OFF (VQ_OFF + 1)
#define IDX_OFF (VQ_OFF + 2)

// workspace float offsets
#define WS_ACC 0
#define WS_CNT 1                        // int: finalizer-blocks-done counter
#define WS_GCNT 2                       // 512 ints: per-voxel-group arrivals
#define WS_ESQH 516                     // 8192 floats: ||e||^2 / 2
#define WS_KEY  (WS_ESQH + N_CODES)     // 8708: 32768 u64 packed (dist,idx)
#define WS_EHI  (WS_KEY + 2 * N_VOX)    // 74244: hi-plane f16 (1 MB, swizzled)
#define WS_ELO  (WS_EHI + N_CODES * DIM / 2)   // lo-plane f16 (1 MB)
// total ws: (74244 + 524288) * 4 B = 2,394,128 bytes

typedef _Float16 half8 __attribute__((ext_vector_type(8)));
typedef float floatx4 __attribute__((ext_vector_type(4)));

// async global->LDS; lds dest is wave-uniform base (+lane*size), global src per-lane
__device__ inline void gld16(const void* g, void* l) {
  __builtin_amdgcn_global_load_lds(
      (const __attribute__((address_space(1))) unsigned int*)g,
      (__attribute__((address_space(3))) unsigned int*)l, 16, 0, 0);
}
__device__ inline void gld4(const void* g, void* l) {
  __builtin_amdgcn_global_load_lds(
      (const __attribute__((address_space(1))) unsigned int*)g,
      (__attribute__((address_space(3))) unsigned int*)l, 4, 0, 0);
}

__device__ __forceinline__ floatx4 mfma16(half8 a, half8 b, floatx4 c) {
  return __builtin_amdgcn_mfma_f32_16x16x32_f16(a, b, c, 0, 0, 0);
}

// order-preserving pack: smaller distance (= -v) -> smaller u64; ties -> lower code
__device__ __forceinline__ unsigned long long packKey(float v, int code) {
  float t = -v;
  unsigned u = __float_as_uint(t);
  u = (u & 0x80000000u) ? ~u : (u | 0x80000000u);
  return ((unsigned long long)u << 32) | (unsigned)code;
}

// ---------------------------------------------------------------- k_cvt
// Pre-convert codebook to hi/lo f16 planes (XOR-swizzled 16B chunks) + esq/2.
// Also initializes all ws control state (ws is poisoned each run).
__global__ __launch_bounds__(256) void k_cvt(const float* __restrict__ e,
                                             float* __restrict__ ws) {
  int gid = blockIdx.x * 256 + threadIdx.x;
  if (gid == 0) { ws[WS_ACC] = 0.f; ((int*)ws)[WS_CNT] = 0; }
  if (gid < 512) ((int*)ws)[WS_GCNT + gid] = 0;
  if (gid < N_VOX) ((unsigned long long*)(ws + WS_KEY))[gid] = ~0ULL;

  int row = gid >> 3, c = gid & 7;
  const float* src = e + (size_t)row * DIM + c * 8;
  float4 a = *(const float4*)src;
  float4 b = *(const float4*)(src + 4);
  float x[8] = {a.x, a.y, a.z, a.w, b.x, b.y, b.z, b.w};
  float s = 0.f;
  half8 hv, lv;
  #pragma unroll
  for (int j = 0; j < 8; ++j) {
    s += x[j] * x[j];                        // esq in full fp32 from originals
    _Float16 h = (_Float16)x[j];
    hv[j] = h;
    lv[j] = (_Float16)(x[j] - (float)h);
  }
  s += __shfl_xor(s, 1); s += __shfl_xor(s, 2); s += __shfl_xor(s, 4);
  if (c == 0) ws[WS_ESQH + row] = 0.5f * s;
  int p = (c + row) & 7;                     // rotate swizzle within row
  ((half8*)(ws + WS_EHI))[row * 8 + p] = hv;
  ((half8*)(ws + WS_ELO))[row * 8 + p] = lv;
}

// ---------------------------------------------------------------- k_argmin
// Grid: 512 voxel-groups x 4 code-quarters = 2048 blocks (4 blocks/CU -> 16
// waves/CU; independent barrier gangs interleave to hide staging latency).
// Block: 64 voxels x 2048 codes, 4 waves = 2 voxel-groups(32) x 2 code-halves.
// 64-code LDS tiles, double-buffered (34.5 KB total), swizzled (0 conflicts).
// Distance surrogate: s = dot - esq/2 (maximize); esq/2 folded into MFMA C-init.
// dot via 3-term f16 split: hh + hl + lh.
// Cross-block merge: packed u64 atomicMin per voxel; 4th-arriving block per
// voxel-group finalizes (gather + Q + idx + loss); 512th finalizer writes scalars.
__global__ __launch_bounds__(256, 4) void k_argmin(const float* __restrict__ z,
                                                   const float* __restrict__ e,
                                                   float* __restrict__ ws,
                                                   float* __restrict__ out) {
  __shared__ __align__(16) _Float16 sBhi[2][64 * 64];   // 16 KB
  __shared__ __align__(16) _Float16 sBlo[2][64 * 64];   // 16 KB
  __shared__ float sEsq[2][64];
  __shared__ float sMval[4][32];
  __shared__ int   sMidx[4][32];
  __shared__ int   sWin[64];
  __shared__ float sWsum[4];
  __shared__ int   sFin;

  const int tid  = threadIdx.x;
  const int lane = tid & 63;
  const int wave = tid >> 6;
  const int n16  = lane & 15;
  const int quad = lane >> 4;
  const int vgrp = wave >> 1;      // which 32-voxel group
  const int chalf = wave & 1;      // which 32-code half of the 64-code tile
  const int grp = blockIdx.x >> 2; // voxel group
  const int qtr = blockIdx.x & 3;  // code quarter
  const int vb  = grp * 64;
  const int cq  = qtr * 2048;

  const char* ehi_b = (const char*)(ws + WS_EHI);
  const char* elo_b = (const char*)(ws + WS_ELO);
  const char* esq_b = (const char*)(ws + WS_ESQH);
  unsigned long long* keyP = (unsigned long long*)(ws + WS_KEY);

  // A fragments: 32 voxels x 64 dims, hi/lo. A[m][kc]: row=n16, k=quad*8+j
  half8 ahi[2][2], alo[2][2];
  #pragma unroll
  for (int m = 0; m < 2; ++m)
    #pragma unroll
    for (int kc = 0; kc < 2; ++kc) {
      const float* src = z + (size_t)(vb + vgrp * 32 + m * 16 + n16) * DIM
                       + kc * 32 + quad * 8;
      float4 a = *(const float4*)src;
      float4 b = *(const float4*)(src + 4);
      float x[8] = {a.x, a.y, a.z, a.w, b.x, b.y, b.z, b.w};
      #pragma unroll
      for (int j = 0; j < 8; ++j) {
        _Float16 h = (_Float16)x[j];
        ahi[m][kc][j] = h;
        alo[m][kc][j] = (_Float16)(x[j] - (float)h);
      }
    }

  float bmax[2][4]; int bidx[2][4];
  #pragma unroll
  for (int m = 0; m < 2; ++m)
    #pragma unroll
    for (int r = 0; r < 4; ++r) { bmax[m][r] = -FLT_MAX; bidx[m][r] = 0; }

  // swizzled chunk offsets (f16 units) for this lane's B-row reads
  const int s0 = ((quad + n16) & 7) * 8;          // kc=0 chunk
  const int s1 = ((quad + 4 + n16) & 7) * 8;      // kc=1 chunk

  // stage one 64-code tile (hi+lo planes + esq) into buffer buf
  auto stage = [&](int buf, int ct) {
    const size_t cbb = (size_t)(cq + ct * 64) * 128;   // bytes per plane-tile
    const int off = wave * 2048;                       // wave-uniform LDS base
    gld16(ehi_b + cbb + off + lane * 16, (char*)sBhi[buf] + off);
    gld16(ehi_b + cbb + off + 1024 + lane * 16, (char*)sBhi[buf] + off + 1024);
    gld16(elo_b + cbb + off + lane * 16, (char*)sBlo[buf] + off);
    gld16(elo_b + cbb + off + 1024 + lane * 16, (char*)sBlo[buf] + off + 1024);
    if (wave == 0)
      gld4(esq_b + (size_t)(cq + ct * 64) * 4 + lane * 4, (char*)sEsq[buf]);
  };

  stage(0, 0);
  __syncthreads();

  for (int ct = 0; ct < 32; ++ct) {
    const int cur = ct & 1;
    if (ct < 31) stage(cur ^ 1, ct + 1);          // prefetch next tile (async)

    const _Float16* bhiP = sBhi[cur];
    const _Float16* bloP = sBlo[cur];
    const float*    esqP = sEsq[cur];
    const int cbase = cq + ct * 64;

    #pragma unroll
    for (int t = 0; t < 2; ++t) {
      const int row = chalf * 32 + t * 16 + n16;
      half8 bh0 = *(const half8*)&bhiP[row * 64 + s0];
      half8 bh1 = *(const half8*)&bhiP[row * 64 + s1];
      half8 bl0 = *(const half8*)&bloP[row * 64 + s0];
      half8 bl1 = *(const half8*)&bloP[row * 64 + s1];
      float eh = esqP[row];
      int code = cbase + row;
      #pragma unroll
      for (int m = 0; m < 2; ++m) {
        floatx4 acc = {-eh, -eh, -eh, -eh};
        acc = mfma16(ahi[m][0], bh0, acc);
        acc = mfma16(ahi[m][1], bh1, acc);
        acc = mfma16(ahi[m][0], bl0, acc);
        acc = mfma16(ahi[m][1], bl1, acc);
        acc = mfma16(alo[m][0], bh0, acc);
        acc = mfma16(alo[m][1], bh1, acc);
        // C layout: col = lane&15 (this lane's code), row = quad*4 + r (voxel)
        #pragma unroll
        for (int r = 0; r < 4; ++r)
          if (acc[r] > bmax[m][r]) { bmax[m][r] = acc[r]; bidx[m][r] = code; }
      }
    }
    __syncthreads();     // staging for ct+1 done + all reads of cur finished
  }

  // reduce across the 16 lanes (n16 = code col) holding each voxel's partials
  #pragma unroll
  for (int m = 0; m < 2; ++m)
    #pragma unroll
    for (int r = 0; r < 4; ++r) {
      float v = bmax[m][r]; int i = bidx[m][r];
      #pragma unroll
      for (int off = 1; off < 16; off <<= 1) {
        float ov = __shfl_xor(v, off);
        int   oi = __shfl_xor(i, off);
        if (ov > v || (ov == v && oi < i)) { v = ov; i = oi; }
      }
      if (n16 == 0) {
        int v32 = m * 16 + quad * 4 + r;
        sMval[wave][v32] = v;
        sMidx[wave][v32] = i;
      }
    }
  __syncthreads();

  // merge the two code-halves, publish packed (dist,idx) via atomicMin
  if (tid < 64) {
    int vg = tid >> 5, vi = tid & 31;
    float v0 = sMval[vg * 2][vi],  v1 = sMval[vg * 2 + 1][vi];
    int   i0 = sMidx[vg * 2][vi],  i1 = sMidx[vg * 2 + 1][vi];
    bool p1 = (v1 > v0) || (v1 == v0 && i1 < i0);
    float v = p1 ? v1 : v0;
    int   i = p1 ? i1 : i0;
    atomicMin(keyP + vb + tid, packKey(v, i));
  }
  __syncthreads();
  if (tid == 0) {
    __threadfence();
    int old = atomicAdd((int*)ws + WS_GCNT + grp, 1);
    sFin = (old == 3);                 // 4th arrival finalizes this group
  }
  __syncthreads();
  if (!sFin) return;

  // finalize: read merged winners, gather quantized rows, loss
  if (tid < 64) {
    unsigned long long k = atomicAdd(keyP + vb + tid, 0ULL);   // coherent read
    int code = (int)(unsigned)(k & 0xFFFFFFFFu);
    sWin[tid] = code;
    out[IDX_OFF + vb + tid] = (float)code;
  }
  __syncthreads();
  {
    const int vox = tid >> 2;
    const int dc = (tid & 3) * 16;
    const int gi = sWin[vox];
    const float* er = e + (size_t)gi * DIM + dc;
    const float* zr = z + (size_t)(vb + vox) * DIM + dc;
    float* qr = out + Q_OFF + (size_t)(vb + vox) * DIM + dc;
    float local = 0.f;
    #pragma unroll
    for (int j = 0; j < 4; ++j) {
      float4 e4 = *(const float4*)(er + j * 4);
      float4 z4 = *(const float4*)(zr + j * 4);
      *(float4*)(qr + j * 4) = e4;
      float dx = z4.x - e4.x, dy = z4.y - e4.y, dz = z4.z - e4.z, dw = z4.w - e4.w;
      local += dx * dx + dy * dy + dz * dz + dw * dw;
    }
    #pragma unroll
    for (int off = 32; off; off >>= 1) local += __shfl_xor(local, off);
    if ((tid & 63) == 0) sWsum[wave] = local;
    __syncthreads();
    if (tid == 0) {
      float bs = sWsum[0] + sWsum[1] + sWsum[2] + sWsum[3];
      atomicAdd(ws + WS_ACC, bs);            // device-scope
      __threadfence();
      int done = atomicAdd((int*)ws + WS_CNT, 1);
      if (done == 511) {                     // last finalizer writes scalars
        float s = atomicAdd(ws + WS_ACC, 0.f);   // atomic read (coherent)
        float mv = s * (1.0f / (float)(N_VOX * DIM));
        out[VQ_OFF] = mv;   // vq_loss
        out[CM_OFF] = mv;   // commitment_loss (identical forward value)
      }
    }
  }
}

// ----------------------------------------------------------------
extern "C" void kernel_launch(void* const* d_in, const int* in_sizes, int n_in,
                              void* d_out, int out_size, void* d_ws, size_t ws_size,
                              hipStream_t stream) {
  const float* z = (const float*)d_in[0];
  const float* e = (const float*)d_in[1];
  float* out = (float*)d_out;
  float* ws = (float*)d_ws;

  k_cvt<<<(N_CODES * 8) / 256, 256, 0, stream>>>(e, ws);
  k_argmin<<<(N_VOX / 64) * 4, 256, 0, stream>>>(z, e, ws, out);
}

// Round 4
// 216.997 us; speedup vs baseline: 1.2485x; 1.2485x over previous
//
#include <hip/hip_runtime.h>
#include <float.h>

#define N_VOX 32768
#define N_CODES 8192
#define DIM 64

// output float offsets (flat, in return order)
#define Q_OFF 0
#define VQ_OFF (N_VOX * DIM)      // 2097152
#define CM_OFF (VQ_OFF + 1)
#define IDX_OFF (VQ_OFF + 2)

// workspace float offsets
#define WS_ACC 0
#define WS_CNT 1                      // int: blocks-done counter
#define WS_ESQH 64                    // 8192 floats: ||e||^2 / 2
#define WS_IDX (WS_ESQH + N_CODES)    // (unused, layout kept)
#define WS_EHI (WS_IDX + N_VOX)       // codebook hi-plane f16 (1 MB, swizzled)
#define WS_ELO (WS_EHI + N_CODES * DIM / 2)  // lo-plane f16 (1 MB)

typedef _Float16 half8 __attribute__((ext_vector_type(8)));
typedef float floatx4 __attribute__((ext_vector_type(4)));

// async global->LDS; lds dest is wave-uniform base (+lane*size), global src per-lane
__device__ inline void gld16(const void* g, void* l) {
  __builtin_amdgcn_global_load_lds(
      (const __attribute__((address_space(1))) unsigned int*)g,
      (__attribute__((address_space(3))) unsigned int*)l, 16, 0, 0);
}
__device__ inline void gld4(const void* g, void* l) {
  __builtin_amdgcn_global_load_lds(
      (const __attribute__((address_space(1))) unsigned int*)g,
      (__attribute__((address_space(3))) unsigned int*)l, 4, 0, 0);
}

__device__ __forceinline__ floatx4 mfma16(half8 a, half8 b, floatx4 c) {
  return __builtin_amdgcn_mfma_f32_16x16x32_f16(a, b, c, 0, 0, 0);
}

// ---------------------------------------------------------------- k_cvt
// Pre-convert codebook to hi/lo f16 planes (XOR-swizzled 16B chunks) + esq/2.
__global__ __launch_bounds__(256) void k_cvt(const float* __restrict__ e,
                                             float* __restrict__ ws) {
  int gid = blockIdx.x * 256 + threadIdx.x;
  if (gid == 0) {                            // ws is poisoned each run
    ws[WS_ACC] = 0.f;
    ((int*)ws)[WS_CNT] = 0;
  }
  int row = gid >> 3, c = gid & 7;
  const float* src = e + (size_t)row * DIM + c * 8;
  float4 a = *(const float4*)src;
  float4 b = *(const float4*)(src + 4);
  float x[8] = {a.x, a.y, a.z, a.w, b.x, b.y, b.z, b.w};
  float s = 0.f;
  half8 hv, lv;
  #pragma unroll
  for (int j = 0; j < 8; ++j) {
    s += x[j] * x[j];                        // esq in full fp32 from originals
    _Float16 h = (_Float16)x[j];
    hv[j] = h;
    lv[j] = (_Float16)(x[j] - (float)h);
  }
  s += __shfl_xor(s, 1); s += __shfl_xor(s, 2); s += __shfl_xor(s, 4);
  if (c == 0) ws[WS_ESQH + row] = 0.5f * s;
  int p = (c + row) & 7;                     // rotate swizzle within row
  ((half8*)(ws + WS_EHI))[row * 8 + p] = hv;
  ((half8*)(ws + WS_ELO))[row * 8 + p] = lv;
}

// ---------------------------------------------------------------- k_argmin
// r1 structure, LDS tile 128 -> 64 codes: 35 KB LDS -> 4 blocks/CU (16
// waves/CU; 4 independent barrier gangs per SIMD interleave to hide ds_read
// latency + barrier skew -- r1's 2 waves/SIMD could not).
// Block: 64 voxels x all 8192 codes, 4 waves = 2 voxel-groups(32) x 2
// 32-code halves of the 64-code tile. Double-buffered, swizzled (0 conflicts).
// Distance surrogate: s = dot - esq/2 (maximize); esq/2 folded into MFMA C-init.
// dot via 3-term f16 split: hh + hl + lh.
__global__ __launch_bounds__(256, 4) void k_argmin(const float* __restrict__ z,
                                                   const float* __restrict__ e,
                                                   float* __restrict__ ws,
                                                   float* __restrict__ out) {
  __shared__ __align__(16) _Float16 sBhi[2][64 * 64];   // 16 KB
  __shared__ __align__(16) _Float16 sBlo[2][64 * 64];   // 16 KB
  __shared__ float sEsq[2][64];                          // 512 B
  __shared__ float sMval[128];
  __shared__ int   sMidx[128];
  __shared__ int   sWin[64];
  __shared__ float sWsum[4];

  const int tid  = threadIdx.x;
  const int lane = tid & 63;
  const int wave = tid >> 6;
  const int n16  = lane & 15;
  const int quad = lane >> 4;
  const int vgrp = wave >> 1;      // which 32-voxel group
  const int chalf = wave & 1;      // which 32-code half of the 64-code tile
  const int vb = blockIdx.x * 64;

  const char* ehi_b = (const char*)(ws + WS_EHI);
  const char* elo_b = (const char*)(ws + WS_ELO);
  const char* esq_b = (const char*)(ws + WS_ESQH);

  // A fragments: 32 voxels x 64 dims, hi/lo. A[m][kc]: row=n16, k=quad*8+j
  half8 ahi[2][2], alo[2][2];
  #pragma unroll
  for (int m = 0; m < 2; ++m)
    #pragma unroll
    for (int kc = 0; kc < 2; ++kc) {
      const float* src = z + (size_t)(vb + vgrp * 32 + m * 16 + n16) * DIM
                       + kc * 32 + quad * 8;
      float4 a = *(const float4*)src;
      float4 b = *(const float4*)(src + 4);
      float x[8] = {a.x, a.y, a.z, a.w, b.x, b.y, b.z, b.w};
      #pragma unroll
      for (int j = 0; j < 8; ++j) {
        _Float16 h = (_Float16)x[j];
        ahi[m][kc][j] = h;
        alo[m][kc][j] = (_Float16)(x[j] - (float)h);
      }
    }

  float bmax[2][4]; int bidx[2][4];
  #pragma unroll
  for (int m = 0; m < 2; ++m)
    #pragma unroll
    for (int r = 0; r < 4; ++r) { bmax[m][r] = -FLT_MAX; bidx[m][r] = 0; }

  // swizzled chunk offsets (f16 units) for this lane's B-row reads
  const int s0 = ((quad + n16) & 7) * 8;          // kc=0 chunk
  const int s1 = ((quad + 4 + n16) & 7) * 8;      // kc=1 chunk

  // stage one 64-code tile (hi+lo planes + esq) into buffer buf
  auto stage = [&](int buf, int ct) {
    const size_t cbb = (size_t)ct * 64 * 128;          // bytes per plane-tile
    const int off = wave * 2048;                       // wave-uniform LDS base
    gld16(ehi_b + cbb + off + lane * 16, (char*)sBhi[buf] + off);
    gld16(ehi_b + cbb + off + 1024 + lane * 16, (char*)sBhi[buf] + off + 1024);
    gld16(elo_b + cbb + off + lane * 16, (char*)sBlo[buf] + off);
    gld16(elo_b + cbb + off + 1024 + lane * 16, (char*)sBlo[buf] + off + 1024);
    if (wave == 0)
      gld4(esq_b + (size_t)ct * 256 + lane * 4, (char*)sEsq[buf]);
  };

  stage(0, 0);
  __syncthreads();

  for (int ct = 0; ct < 128; ++ct) {
    const int cur = ct & 1;
    if (ct < 127) stage(cur ^ 1, ct + 1);         // prefetch next tile (async)

    const _Float16* bhiP = sBhi[cur];
    const _Float16* bloP = sBlo[cur];
    const float*    esqP = sEsq[cur];
    const int cbase = ct * 64;

    #pragma unroll
    for (int t = 0; t < 2; ++t) {
      const int row = chalf * 32 + t * 16 + n16;
      half8 bh0 = *(const half8*)&bhiP[row * 64 + s0];
      half8 bh1 = *(const half8*)&bhiP[row * 64 + s1];
      half8 bl0 = *(const half8*)&bloP[row * 64 + s0];
      half8 bl1 = *(const half8*)&bloP[row * 64 + s1];
      float eh = esqP[row];
      int code = cbase + row;
      __builtin_amdgcn_s_setprio(1);
      #pragma unroll
      for (int m = 0; m < 2; ++m) {
        floatx4 acc = {-eh, -eh, -eh, -eh};
        acc = mfma16(ahi[m][0], bh0, acc);
        acc = mfma16(ahi[m][1], bh1, acc);
        acc = mfma16(ahi[m][0], bl0, acc);
        acc = mfma16(ahi[m][1], bl1, acc);
        acc = mfma16(alo[m][0], bh0, acc);
        acc = mfma16(alo[m][1], bh1, acc);
        // C layout: col = lane&15 (this lane's code), row = quad*4 + r (voxel)
        #pragma unroll
        for (int r = 0; r < 4; ++r)
          if (acc[r] > bmax[m][r]) { bmax[m][r] = acc[r]; bidx[m][r] = code; }
      }
      __builtin_amdgcn_s_setprio(0);
    }
    __syncthreads();     // staging for ct+1 done + all reads of cur finished
  }

  // reduce across the 16 lanes (n16 = code col) holding each voxel's partials
  #pragma unroll
  for (int m = 0; m < 2; ++m)
    #pragma unroll
    for (int r = 0; r < 4; ++r) {
      float v = bmax[m][r]; int i = bidx[m][r];
      #pragma unroll
      for (int off = 1; off < 16; off <<= 1) {
        float ov = __shfl_xor(v, off);
        int   oi = __shfl_xor(i, off);
        if (ov > v || (ov == v && oi < i)) { v = ov; i = oi; }
      }
      if (n16 == 0) {
        int vox = vgrp * 32 + m * 16 + quad * 4 + r;
        sMval[chalf * 64 + vox] = v;
        sMidx[chalf * 64 + vox] = i;
      }
    }
  __syncthreads();

  // merge the two code-halves, publish winner index
  if (tid < 64) {
    float v0 = sMval[tid], v1 = sMval[64 + tid];
    int   i0 = sMidx[tid], i1 = sMidx[64 + tid];
    bool p1 = (v1 > v0) || (v1 == v0 && i1 < i0);
    int w = p1 ? i1 : i0;
    sWin[tid] = w;
    out[IDX_OFF + vb + tid] = (float)w;
  }
  __syncthreads();

  // fused k_out: gather quantized rows (exact fp32), accumulate (z-q)^2
  {
    const int vox = tid >> 2;
    const int dc = (tid & 3) * 16;
    const int gi = sWin[vox];
    const float* er = e + (size_t)gi * DIM + dc;
    const float* zr = z + (size_t)(vb + vox) * DIM + dc;
    float* qr = out + Q_OFF + (size_t)(vb + vox) * DIM + dc;
    float local = 0.f;
    #pragma unroll
    for (int j = 0; j < 4; ++j) {
      float4 e4 = *(const float4*)(er + j * 4);
      float4 z4 = *(const float4*)(zr + j * 4);
      *(float4*)(qr + j * 4) = e4;
      float dx = z4.x - e4.x, dy = z4.y - e4.y, dz = z4.z - e4.z, dw = z4.w - e4.w;
      local += dx * dx + dy * dy + dz * dz + dw * dw;
    }
    #pragma unroll
    for (int off = 32; off; off >>= 1) local += __shfl_xor(local, off);
    if ((tid & 63) == 0) sWsum[wave] = local;
    __syncthreads();
    if (tid == 0) {
      float bs = sWsum[0] + sWsum[1] + sWsum[2] + sWsum[3];
      atomicAdd(ws + WS_ACC, bs);            // device-scope
      __threadfence();
      int done = atomicAdd((int*)ws + WS_CNT, 1);
      if (done == (int)gridDim.x - 1) {      // last block: finalize scalars
        float s = atomicAdd(ws + WS_ACC, 0.f);   // atomic read (coherent)
        float mv = s * (1.0f / (float)(N_VOX * DIM));
        out[VQ_OFF] = mv;   // vq_loss
        out[CM_OFF] = mv;   // commitment_loss (identical forward value)
      }
    }
  }
}

// ----------------------------------------------------------------
extern "C" void kernel_launch(void* const* d_in, const int* in_sizes, int n_in,
                              void* d_out, int out_size, void* d_ws, size_t ws_size,
                              hipStream_t stream) {
  const float* z = (const float*)d_in[0];
  const float* e = (const float*)d_in[1];
  float* out = (float*)d_out;
  float* ws = (float*)d_ws;

  k_cvt<<<(N_CODES * 8) / 256, 256, 0, stream>>>(e, ws);
  k_argmin<<<N_VOX / 64, 256, 0, stream>>>(z, e, ws, out);
}

// Round 5
// 199.741 us; speedup vs baseline: 1.3564x; 1.0864x over previous
//
#include <hip/hip_runtime.h>
#include <float.h>

#define N_VOX 32768
#define N_CODES 8192
#define DIM 64

// output float offsets (flat, in return order)
#define Q_OFF 0
#define VQ_OFF (N_VOX * DIM)      // 2097152
#define CM_OFF (VQ_OFF + 1)
#define IDX_OFF (VQ_OFF + 2)

// workspace float offsets
#define WS_ACC 0
#define WS_CNT 1                      // int: blocks-done counter
#define WS_ESQH 64                    // 8192 floats: -||e||^2 / 2  (NEGATED)
#define WS_IDX (WS_ESQH + N_CODES)    // (unused, layout kept)
#define WS_EHI (WS_IDX + N_VOX)       // codebook hi-plane f16 (1 MB, swizzled)
#define WS_ELO (WS_EHI + N_CODES * DIM / 2)  // lo-plane f16 (1 MB)

typedef _Float16 half8 __attribute__((ext_vector_type(8)));
typedef float floatx4 __attribute__((ext_vector_type(4)));

// async global->LDS; lds dest is wave-uniform base (+lane*size), global src per-lane
__device__ inline void gld16(const void* g, void* l) {
  __builtin_amdgcn_global_load_lds(
      (const __attribute__((address_space(1))) unsigned int*)g,
      (__attribute__((address_space(3))) unsigned int*)l, 16, 0, 0);
}
__device__ inline void gld4(const void* g, void* l) {
  __builtin_amdgcn_global_load_lds(
      (const __attribute__((address_space(1))) unsigned int*)g,
      (__attribute__((address_space(3))) unsigned int*)l, 4, 0, 0);
}

__device__ __forceinline__ floatx4 mfma16(half8 a, half8 b, floatx4 c) {
  return __builtin_amdgcn_mfma_f32_16x16x32_f16(a, b, c, 0, 0, 0);
}

// ---------------------------------------------------------------- k_cvt
// Pre-convert codebook to hi/lo f16 planes (XOR-swizzled 16B chunks) +
// NEGATED esq/2 (folds into MFMA C-init with zero VALU in the hot loop).
__global__ __launch_bounds__(256) void k_cvt(const float* __restrict__ e,
                                             float* __restrict__ ws) {
  int gid = blockIdx.x * 256 + threadIdx.x;
  if (gid == 0) {                            // ws is poisoned each run
    ws[WS_ACC] = 0.f;
    ((int*)ws)[WS_CNT] = 0;
  }
  int row = gid >> 3, c = gid & 7;
  const float* src = e + (size_t)row * DIM + c * 8;
  float4 a = *(const float4*)src;
  float4 b = *(const float4*)(src + 4);
  float x[8] = {a.x, a.y, a.z, a.w, b.x, b.y, b.z, b.w};
  float s = 0.f;
  half8 hv, lv;
  #pragma unroll
  for (int j = 0; j < 8; ++j) {
    s += x[j] * x[j];                        // esq in full fp32 from originals
    _Float16 h = (_Float16)x[j];
    hv[j] = h;
    lv[j] = (_Float16)(x[j] - (float)h);
  }
  s += __shfl_xor(s, 1); s += __shfl_xor(s, 2); s += __shfl_xor(s, 4);
  if (c == 0) ws[WS_ESQH + row] = -0.5f * s;
  int p = (c + row) & 7;                     // rotate swizzle within row
  ((half8*)(ws + WS_EHI))[row * 8 + p] = hv;
  ((half8*)(ws + WS_ELO))[row * 8 + p] = lv;
}

// ---------------------------------------------------------------- k_argmin
// r1 shell: 512 blocks x 64 voxels x all 8192 codes, 128-code LDS tiles,
// double-buffered (68 KB, 2 blocks/CU), 64 barriers, fused epilogue.
// NEW wave decomposition: each wave = ALL 64 voxels x a disjoint 32-code
// quarter of the tile -> LDS ds_reads halve (no cross-wave B duplication).
// NEW split accumulators: the 6 MFMA terms (hh+hl+lh over kc0/kc1) go into
// two independent 3-chains per (t,m) -> 8 independent chains/wave, dep-stall
// largely eliminated. Score s = dot - esq/2 (maximize); -esq/2 in C-init.
__global__ __launch_bounds__(256, 2) void k_argmin(const float* __restrict__ z,
                                                   const float* __restrict__ e,
                                                   float* __restrict__ ws,
                                                   float* __restrict__ out) {
  __shared__ __align__(16) _Float16 sBhi[2][128 * 64];   // 32 KB
  __shared__ __align__(16) _Float16 sBlo[2][128 * 64];   // 32 KB
  __shared__ float sEsq[2][128];                          // 1 KB
  __shared__ float sMval[4][64];
  __shared__ int   sMidx[4][64];
  __shared__ int   sWin[64];
  __shared__ float sWsum[4];

  const int tid  = threadIdx.x;
  const int lane = tid & 63;
  const int wave = tid >> 6;       // which 32-code quarter of the 128-tile
  const int n16  = lane & 15;
  const int quad = lane >> 4;
  const int vb = blockIdx.x * 64;

  const char* ehi_b = (const char*)(ws + WS_EHI);
  const char* elo_b = (const char*)(ws + WS_ELO);
  const char* esq_b = (const char*)(ws + WS_ESQH);

  // A fragments: ALL 64 voxels x 64 dims, hi/lo. A[m][kc]: row=n16, k=quad*8+j
  half8 ahi[4][2], alo[4][2];
  #pragma unroll
  for (int m = 0; m < 4; ++m)
    #pragma unroll
    for (int kc = 0; kc < 2; ++kc) {
      const float* src = z + (size_t)(vb + m * 16 + n16) * DIM
                       + kc * 32 + quad * 8;
      float4 a = *(const float4*)src;
      float4 b = *(const float4*)(src + 4);
      float x[8] = {a.x, a.y, a.z, a.w, b.x, b.y, b.z, b.w};
      #pragma unroll
      for (int j = 0; j < 8; ++j) {
        _Float16 h = (_Float16)x[j];
        ahi[m][kc][j] = h;
        alo[m][kc][j] = (_Float16)(x[j] - (float)h);
      }
    }

  float bmax[4][4]; int bidx[4][4];
  #pragma unroll
  for (int m = 0; m < 4; ++m)
    #pragma unroll
    for (int r = 0; r < 4; ++r) { bmax[m][r] = -FLT_MAX; bidx[m][r] = 0; }

  // swizzled chunk offsets (f16 units) for this lane's B-row reads
  const int s0 = ((quad + n16) & 7) * 8;          // kc=0 chunk
  const int s1 = ((quad + 4 + n16) & 7) * 8;      // kc=1 chunk

  // stage one 128-code tile (hi+lo planes + esq) into buffer buf
  auto stage = [&](int buf, int ct) {
    const size_t cbb = (size_t)ct * 128 * 128;    // bytes per plane-tile
    #pragma unroll
    for (int r = 0; r < 4; ++r) {
      int off = (r * 4 + wave) * 1024;            // wave-uniform LDS base
      gld16(ehi_b + cbb + off + lane * 16, (char*)sBhi[buf] + off);
      gld16(elo_b + cbb + off + lane * 16, (char*)sBlo[buf] + off);
    }
    if (wave == 0) {
      gld4(esq_b + (size_t)ct * 512 + lane * 4, (char*)sEsq[buf]);
      gld4(esq_b + (size_t)ct * 512 + 256 + lane * 4, (char*)sEsq[buf] + 256);
    }
  };

  stage(0, 0);
  __syncthreads();

  for (int ct = 0; ct < 64; ++ct) {
    const int cur = ct & 1;
    if (ct < 63) stage(cur ^ 1, ct + 1);          // prefetch next tile (async)

    const _Float16* bhiP = sBhi[cur];
    const _Float16* bloP = sBlo[cur];
    const float*    esqP = sEsq[cur];
    const int cbase = ct * 128;

    #pragma unroll
    for (int t = 0; t < 2; ++t) {
      const int row = wave * 32 + t * 16 + n16;   // this wave's code rows
      half8 bh0 = *(const half8*)&bhiP[row * 64 + s0];
      half8 bh1 = *(const half8*)&bhiP[row * 64 + s1];
      half8 bl0 = *(const half8*)&bloP[row * 64 + s0];
      half8 bl1 = *(const half8*)&bloP[row * 64 + s1];
      float nh = esqP[row];                       // -esq/2 for this code
      int code = cbase + row;
      __builtin_amdgcn_s_setprio(1);
      #pragma unroll
      for (int m = 0; m < 4; ++m) {
        floatx4 acc0 = {nh, nh, nh, nh};
        floatx4 acc1 = {0.f, 0.f, 0.f, 0.f};
        // two independent 3-chains (hh0,hh1,hl0 | hl1,lh0,lh1)
        acc0 = mfma16(ahi[m][0], bh0, acc0);
        acc1 = mfma16(ahi[m][1], bh1, acc1);
        acc0 = mfma16(ahi[m][0], bl0, acc0);
        acc1 = mfma16(ahi[m][1], bl1, acc1);
        acc0 = mfma16(alo[m][0], bh0, acc0);
        acc1 = mfma16(alo[m][1], bh1, acc1);
        // C layout: col = lane&15 (this lane's code), row = quad*4 + r (voxel)
        #pragma unroll
        for (int r = 0; r < 4; ++r) {
          float tv = acc0[r] + acc1[r];
          if (tv > bmax[m][r]) { bmax[m][r] = tv; bidx[m][r] = code; }
        }
      }
      __builtin_amdgcn_s_setprio(0);
    }
    __syncthreads();     // staging for ct+1 done + all reads of cur finished
  }

  // reduce across the 16 lanes (n16 = code col) holding each voxel's partials
  #pragma unroll
  for (int m = 0; m < 4; ++m)
    #pragma unroll
    for (int r = 0; r < 4; ++r) {
      float v = bmax[m][r]; int i = bidx[m][r];
      #pragma unroll
      for (int off = 1; off < 16; off <<= 1) {
        float ov = __shfl_xor(v, off);
        int   oi = __shfl_xor(i, off);
        if (ov > v || (ov == v && oi < i)) { v = ov; i = oi; }
      }
      if (n16 == 0) {
        sMval[wave][m * 16 + quad * 4 + r] = v;
        sMidx[wave][m * 16 + quad * 4 + r] = i;
      }
    }
  __syncthreads();

  // merge the four code-quarters, publish winner index
  if (tid < 64) {
    float v = sMval[0][tid]; int i = sMidx[0][tid];
    #pragma unroll
    for (int q = 1; q < 4; ++q) {
      float ov = sMval[q][tid]; int oi = sMidx[q][tid];
      if (ov > v || (ov == v && oi < i)) { v = ov; i = oi; }
    }
    sWin[tid] = i;
    out[IDX_OFF + vb + tid] = (float)i;
  }
  __syncthreads();

  // fused k_out: gather quantized rows (exact fp32), accumulate (z-q)^2
  {
    const int vox = tid >> 2;
    const int dc = (tid & 3) * 16;
    const int gi = sWin[vox];
    const float* er = e + (size_t)gi * DIM + dc;
    const float* zr = z + (size_t)(vb + vox) * DIM + dc;
    float* qr = out + Q_OFF + (size_t)(vb + vox) * DIM + dc;
    float local = 0.f;
    #pragma unroll
    for (int j = 0; j < 4; ++j) {
      float4 e4 = *(const float4*)(er + j * 4);
      float4 z4 = *(const float4*)(zr + j * 4);
      *(float4*)(qr + j * 4) = e4;
      float dx = z4.x - e4.x, dy = z4.y - e4.y, dz = z4.z - e4.z, dw = z4.w - e4.w;
      local += dx * dx + dy * dy + dz * dz + dw * dw;
    }
    #pragma unroll
    for (int off = 32; off; off >>= 1) local += __shfl_xor(local, off);
    if ((tid & 63) == 0) sWsum[wave] = local;
    __syncthreads();
    if (tid == 0) {
      float bs = sWsum[0] + sWsum[1] + sWsum[2] + sWsum[3];
      atomicAdd(ws + WS_ACC, bs);            // device-scope
      __threadfence();
      int done = atomicAdd((int*)ws + WS_CNT, 1);
      if (done == (int)gridDim.x - 1) {      // last block: finalize scalars
        float s = atomicAdd(ws + WS_ACC, 0.f);   // atomic read (coherent)
        float mv = s * (1.0f / (float)(N_VOX * DIM));
        out[VQ_OFF] = mv;   // vq_loss
        out[CM_OFF] = mv;   // commitment_loss (identical forward value)
      }
    }
  }
}

// ----------------------------------------------------------------
extern "C" void kernel_launch(void* const* d_in, const int* in_sizes, int n_in,
                              void* d_out, int out_size, void* d_ws, size_t ws_size,
                              hipStream_t stream) {
  const float* z = (const float*)d_in[0];
  const float* e = (const float*)d_in[1];
  float* out = (float*)d_out;
  float* ws = (float*)d_ws;

  k_cvt<<<(N_CODES * 8) / 256, 256, 0, stream>>>(e, ws);
  k_argmin<<<N_VOX / 64, 256, 0, stream>>>(z, e, ws, out);
}